// Round 13
// baseline (316.319 us; speedup 1.0000x reference)
//
#include <hip/hip_runtime.h>
#include <hip/hip_bf16.h>

constexpr int NROW = 8192;
constexpr int INF  = 256;
constexpr int OUTF = 128;
constexpr int KSPLIT = 16;
constexpr int KCHUNK = NROW / KSPLIT; // 512
#define LOG2E 1.4426950408889634f

typedef __bf16 bf16x8 __attribute__((ext_vector_type(8)));
typedef float  f32x4  __attribute__((ext_vector_type(4)));
typedef int    i32x4  __attribute__((ext_vector_type(4)));

// ---------------------------------------------------------------------------
// k1: h = x@W (f32 accum); f1 = (h@a1)*log2e, f2 = (h@a2)*log2e; ht = h^T bf16
// grid: NROW/32 blocks, 256 threads
// ---------------------------------------------------------------------------
__global__ __launch_bounds__(256) void k1(const float* __restrict__ x,
                                          const float* __restrict__ W,
                                          const float* __restrict__ a,
                                          __bf16* __restrict__ ht,
                                          float* __restrict__ f1,
                                          float* __restrict__ f2) {
  __shared__ float xs[32][INF];   // 32 KB
  __shared__ float hs[32][OUTF];  // 16 KB
  const int t  = threadIdx.x;
  const int i0 = blockIdx.x * 32;

  const f32x4* xsrc = reinterpret_cast<const f32x4*>(x + (size_t)i0 * INF);
  f32x4* xdst = reinterpret_cast<f32x4*>(&xs[0][0]);
  #pragma unroll
  for (int u = 0; u < (32 * INF / 4) / 256; ++u)
    xdst[u * 256 + t] = xsrc[u * 256 + t];
  __syncthreads();

  const int c  = t & 127;
  const int rg = t >> 7;  // 0/1 -> rows rg*16 .. rg*16+15
  float acc[16];
  #pragma unroll
  for (int r = 0; r < 16; ++r) acc[r] = 0.f;
  for (int k = 0; k < INF; ++k) {
    float wv = W[k * OUTF + c];
    #pragma unroll
    for (int r = 0; r < 16; ++r) acc[r] += xs[rg * 16 + r][k] * wv;
  }
  #pragma unroll
  for (int r = 0; r < 16; ++r) hs[rg * 16 + r][c] = acc[r];
  __syncthreads();

  const int wv = t >> 6, lane = t & 63;
  for (int r = wv; r < 32; r += 4) {
    float h0 = hs[r][lane * 2], h1 = hs[r][lane * 2 + 1];
    float s1 = h0 * a[lane * 2] + h1 * a[lane * 2 + 1];
    float s2 = h0 * a[OUTF + lane * 2] + h1 * a[OUTF + lane * 2 + 1];
    #pragma unroll
    for (int off = 32; off; off >>= 1) {
      s1 += __shfl_down(s1, off);
      s2 += __shfl_down(s2, off);
    }
    if (lane == 0) { f1[i0 + r] = s1 * LOG2E; f2[i0 + r] = s2 * LOG2E; }
  }

  const int col = t >> 1, seg = t & 1;
  bf16x8 v0, v1;
  #pragma unroll
  for (int r = 0; r < 8; ++r) v0[r] = (__bf16)hs[seg * 16 + r][col];
  #pragma unroll
  for (int r = 0; r < 8; ++r) v1[r] = (__bf16)hs[seg * 16 + 8 + r][col];
  __bf16* hdst = ht + (size_t)col * NROW + i0 + seg * 16;
  *reinterpret_cast<bf16x8*>(hdst)     = v0;
  *reinterpret_cast<bf16x8*>(hdst + 8) = v1;
}

// ---------------------------------------------------------------------------
// katt2: one row per block, 8192 blocks.
// Phase 1 (pure READ): 8 adj NT loads + 8 f2 loads (kept in registers).
// Phase 1.5: block sum-reduce only.
// Phase 2 (pure WRITE): recompute p from register fv; zero loads between
// stores so the in-order vmcnt queue never forces a store drain.
// grid: NROW blocks, 256 threads
// ---------------------------------------------------------------------------
__global__ __launch_bounds__(256) void katt2(const int* __restrict__ adj,
                                             const float* __restrict__ f1,
                                             const float* __restrict__ f2,
                                             float* __restrict__ att) {
  const int i = blockIdx.x;
  const int t = threadIdx.x;
  const int lane = t & 63, wv = t >> 6;
  const float f1i = f1[i];
  const i32x4* arow = reinterpret_cast<const i32x4*>(adj + (size_t)i * NROW);
  const f32x4* f2v  = reinterpret_cast<const f32x4*>(f2);

  // ---- phase 1: pure read stream ----
  unsigned mynibs = 0;
  float acc = 0.f;
  f32x4 fv[8];
  #pragma unroll
  for (int it = 0; it < 8; ++it) {
    i32x4 av = __builtin_nontemporal_load(arow + it * 256 + t);
    fv[it] = f2v[it * 256 + t];
    unsigned nib = (av[0] > 0) | ((av[1] > 0) << 1) | ((av[2] > 0) << 2) |
                   ((av[3] > 0) << 3);
    mynibs |= nib << (it * 4);
    #pragma unroll
    for (int b = 0; b < 4; ++b) {
      float e = f1i + fv[it][b];
      e = e > 0.f ? e : 0.01f * e;
      acc += ((nib >> b) & 1u) ? __builtin_exp2f(e) : 0.f;
    }
  }

  // ---- phase 1.5: row-sum reduction ----
  #pragma unroll
  for (int off = 32; off; off >>= 1) acc += __shfl_down(acc, off);
  __shared__ float red[4];
  if (lane == 0) red[wv] = acc;
  __syncthreads();
  const float inv_s = 1.0f / (red[0] + red[1] + red[2] + red[3]);

  // ---- phase 2: pure write stream (no loads; fv in registers) ----
  f32x4* adst = reinterpret_cast<f32x4*>(att + (size_t)i * NROW);
  #pragma unroll
  for (int it = 0; it < 8; ++it) {
    const unsigned nib = (mynibs >> (it * 4)) & 0xFu;
    f32x4 o;
    #pragma unroll
    for (int b = 0; b < 4; ++b) {
      float e = f1i + fv[it][b];
      e = e > 0.f ? e : 0.01f * e;
      o[b] = ((nib >> b) & 1u) ? __builtin_exp2f(e) * inv_s : 0.f;
    }
    adst[it * 256 + t] = o;
  }
}

// ---------------------------------------------------------------------------
// kpv: PURE GEMM out0 = att @ h. r12 showed MfmaUtil 3.8% / VALUBusy 3.2% /
// occupancy 35% — pure latency starvation, grid-capped at 4 blocks/CU.
// Fix: KSPLIT=16 (grid 2048 = 8 blocks/CU) + launch_bounds(256,8) to pin
// VGPR <= 64 so all 8 blocks (32 waves/CU) are co-resident.
// grid: (NROW/64)*KSPLIT blocks, 256 threads
// ---------------------------------------------------------------------------
__global__ __launch_bounds__(256, 8) void kpv(const __bf16* __restrict__ ht,
                                              const float* __restrict__ att,
                                              float* __restrict__ out0) {
  const int mb = blockIdx.x / KSPLIT;
  const int ks = blockIdx.x % KSPLIT;
  const int t    = threadIdx.x;
  const int w    = t >> 6;
  const int lane = t & 63;
  const int lr = lane & 15;
  const int lc = lane >> 4;
  const int row0 = mb * 64 + w * 16;
  const int arow = row0 + lr;
  const int j0 = ks * KCHUNK;

  const float* abase = att + (size_t)arow * NROW + j0 + lc * 8;
  const __bf16* hbase = ht + (size_t)lr * NROW + j0 + lc * 8;

  f32x4 acc[8];
  #pragma unroll
  for (int n = 0; n < 8; ++n) acc[n] = (f32x4){0.f, 0.f, 0.f, 0.f};

  // prefetch A for kk=0: 4x f32x4 (h=0: cols +0..7, h=1: cols +32..39)
  f32x4 pa0 = *reinterpret_cast<const f32x4*>(abase);
  f32x4 pa1 = *reinterpret_cast<const f32x4*>(abase + 4);
  f32x4 pa2 = *reinterpret_cast<const f32x4*>(abase + 32);
  f32x4 pa3 = *reinterpret_cast<const f32x4*>(abase + 36);

  for (int kk = 0; kk < KCHUNK; kk += 64) {
    const f32x4 ca0 = pa0, ca1 = pa1, ca2 = pa2, ca3 = pa3;
    if (kk + 64 < KCHUNK) {
      const float* ab = abase + kk + 64;
      pa0 = *reinterpret_cast<const f32x4*>(ab);
      pa1 = *reinterpret_cast<const f32x4*>(ab + 4);
      pa2 = *reinterpret_cast<const f32x4*>(ab + 32);
      pa3 = *reinterpret_cast<const f32x4*>(ab + 36);
    }

    bf16x8 afrag[2];
    #pragma unroll
    for (int i2 = 0; i2 < 4; ++i2) {
      afrag[0][i2]     = (__bf16)ca0[i2];
      afrag[0][i2 + 4] = (__bf16)ca1[i2];
      afrag[1][i2]     = (__bf16)ca2[i2];
      afrag[1][i2 + 4] = (__bf16)ca3[i2];
    }

    #pragma unroll
    for (int n = 0; n < 8; ++n) {
      const __bf16* hb = hbase + (size_t)(n * 16) * NROW + kk;
      bf16x8 b0 = *reinterpret_cast<const bf16x8*>(hb);
      bf16x8 b1 = *reinterpret_cast<const bf16x8*>(hb + 32);
      acc[n] = __builtin_amdgcn_mfma_f32_16x16x32_bf16(afrag[0], b0, acc[n], 0, 0, 0);
      acc[n] = __builtin_amdgcn_mfma_f32_16x16x32_bf16(afrag[1], b1, acc[n], 0, 0, 0);
    }
  }

  #pragma unroll
  for (int n = 0; n < 8; ++n) {
    #pragma unroll
    for (int i2 = 0; i2 < 4; ++i2) {
      atomicAdd(&out0[(size_t)(row0 + lc * 4 + i2) * OUTF + n * 16 + lr],
                acc[n][i2]);
    }
  }
}

// ---------------------------------------------------------------------------
extern "C" void kernel_launch(void* const* d_in, const int* in_sizes, int n_in,
                              void* d_out, int out_size, void* d_ws, size_t ws_size,
                              hipStream_t stream) {
  const float* x   = (const float*)d_in[0];
  const int*   adj = (const int*)d_in[1];
  const float* W   = (const float*)d_in[2];
  const float* a   = (const float*)d_in[3];

  float* out0 = (float*)d_out;                       // 8192 x 128
  float* att  = (float*)d_out + (size_t)NROW * OUTF; // 8192 x 8192

  char* ws = (char*)d_ws;
  __bf16* ht = (__bf16*)ws;                               // 2 MB
  float* f1 = (float*)(ws + (2 << 20));
  float* f2 = (float*)(ws + (2 << 20) + 32 * 1024);

  hipMemsetAsync(out0, 0, (size_t)NROW * OUTF * sizeof(float), stream);
  k1<<<NROW / 32, 256, 0, stream>>>(x, W, a, ht, f1, f2);
  katt2<<<NROW, 256, 0, stream>>>(adj, f1, f2, att);
  kpv<<<(NROW / 64) * KSPLIT, 256, 0, stream>>>(ht, att, out0);
}

// Round 14
// 307.306 us; speedup vs baseline: 1.0293x; 1.0293x over previous
//
#include <hip/hip_runtime.h>
#include <hip/hip_bf16.h>

constexpr int NROW = 8192;
constexpr int INF  = 256;
constexpr int OUTF = 128;
constexpr int KSPLIT = 16;
constexpr int KCHUNK = NROW / KSPLIT; // 512
#define LOG2E 1.4426950408889634f

typedef __bf16 bf16x8 __attribute__((ext_vector_type(8)));
typedef float  f32x4  __attribute__((ext_vector_type(4)));
typedef int    i32x4  __attribute__((ext_vector_type(4)));

// ---------------------------------------------------------------------------
// k1: h = x@W (f32 accum); f1 = (h@a1)*log2e, f2 = (h@a2)*log2e; ht = h^T bf16
// grid: NROW/32 blocks, 256 threads
// ---------------------------------------------------------------------------
__global__ __launch_bounds__(256) void k1(const float* __restrict__ x,
                                          const float* __restrict__ W,
                                          const float* __restrict__ a,
                                          __bf16* __restrict__ ht,
                                          float* __restrict__ f1,
                                          float* __restrict__ f2) {
  __shared__ float xs[32][INF];   // 32 KB
  __shared__ float hs[32][OUTF];  // 16 KB
  const int t  = threadIdx.x;
  const int i0 = blockIdx.x * 32;

  const f32x4* xsrc = reinterpret_cast<const f32x4*>(x + (size_t)i0 * INF);
  f32x4* xdst = reinterpret_cast<f32x4*>(&xs[0][0]);
  #pragma unroll
  for (int u = 0; u < (32 * INF / 4) / 256; ++u)
    xdst[u * 256 + t] = xsrc[u * 256 + t];
  __syncthreads();

  const int c  = t & 127;
  const int rg = t >> 7;  // 0/1 -> rows rg*16 .. rg*16+15
  float acc[16];
  #pragma unroll
  for (int r = 0; r < 16; ++r) acc[r] = 0.f;
  for (int k = 0; k < INF; ++k) {
    float wv = W[k * OUTF + c];
    #pragma unroll
    for (int r = 0; r < 16; ++r) acc[r] += xs[rg * 16 + r][k] * wv;
  }
  #pragma unroll
  for (int r = 0; r < 16; ++r) hs[rg * 16 + r][c] = acc[r];
  __syncthreads();

  const int wv = t >> 6, lane = t & 63;
  for (int r = wv; r < 32; r += 4) {
    float h0 = hs[r][lane * 2], h1 = hs[r][lane * 2 + 1];
    float s1 = h0 * a[lane * 2] + h1 * a[lane * 2 + 1];
    float s2 = h0 * a[OUTF + lane * 2] + h1 * a[OUTF + lane * 2 + 1];
    #pragma unroll
    for (int off = 32; off; off >>= 1) {
      s1 += __shfl_down(s1, off);
      s2 += __shfl_down(s2, off);
    }
    if (lane == 0) { f1[i0 + r] = s1 * LOG2E; f2[i0 + r] = s2 * LOG2E; }
  }

  const int col = t >> 1, seg = t & 1;
  bf16x8 v0, v1;
  #pragma unroll
  for (int r = 0; r < 8; ++r) v0[r] = (__bf16)hs[seg * 16 + r][col];
  #pragma unroll
  for (int r = 0; r < 8; ++r) v1[r] = (__bf16)hs[seg * 16 + 8 + r][col];
  __bf16* hdst = ht + (size_t)col * NROW + i0 + seg * 16;
  *reinterpret_cast<bf16x8*>(hdst)     = v0;
  *reinterpret_cast<bf16x8*>(hdst + 8) = v1;
}

// ---------------------------------------------------------------------------
// katt2: one row per block, 8192 blocks.
// Phase 1 (pure READ): 8 adj NT loads + 8 f2 loads (kept in registers).
// Phase 1.5: block sum-reduce only.
// Phase 2 (pure WRITE): recompute p from register fv; zero loads between
// stores so the in-order vmcnt queue never forces a store drain.
// grid: NROW blocks, 256 threads
// ---------------------------------------------------------------------------
__global__ __launch_bounds__(256) void katt2(const int* __restrict__ adj,
                                             const float* __restrict__ f1,
                                             const float* __restrict__ f2,
                                             float* __restrict__ att) {
  const int i = blockIdx.x;
  const int t = threadIdx.x;
  const int lane = t & 63, wv = t >> 6;
  const float f1i = f1[i];
  const i32x4* arow = reinterpret_cast<const i32x4*>(adj + (size_t)i * NROW);
  const f32x4* f2v  = reinterpret_cast<const f32x4*>(f2);

  // ---- phase 1: pure read stream ----
  unsigned mynibs = 0;
  float acc = 0.f;
  f32x4 fv[8];
  #pragma unroll
  for (int it = 0; it < 8; ++it) {
    i32x4 av = __builtin_nontemporal_load(arow + it * 256 + t);
    fv[it] = f2v[it * 256 + t];
    unsigned nib = (av[0] > 0) | ((av[1] > 0) << 1) | ((av[2] > 0) << 2) |
                   ((av[3] > 0) << 3);
    mynibs |= nib << (it * 4);
    #pragma unroll
    for (int b = 0; b < 4; ++b) {
      float e = f1i + fv[it][b];
      e = e > 0.f ? e : 0.01f * e;
      acc += ((nib >> b) & 1u) ? __builtin_exp2f(e) : 0.f;
    }
  }

  // ---- phase 1.5: row-sum reduction ----
  #pragma unroll
  for (int off = 32; off; off >>= 1) acc += __shfl_down(acc, off);
  __shared__ float red[4];
  if (lane == 0) red[wv] = acc;
  __syncthreads();
  const float inv_s = 1.0f / (red[0] + red[1] + red[2] + red[3]);

  // ---- phase 2: pure write stream (no loads; fv in registers) ----
  f32x4* adst = reinterpret_cast<f32x4*>(att + (size_t)i * NROW);
  #pragma unroll
  for (int it = 0; it < 8; ++it) {
    const unsigned nib = (mynibs >> (it * 4)) & 0xFu;
    f32x4 o;
    #pragma unroll
    for (int b = 0; b < 4; ++b) {
      float e = f1i + fv[it][b];
      e = e > 0.f ? e : 0.01f * e;
      o[b] = ((nib >> b) & 1u) ? __builtin_exp2f(e) * inv_s : 0.f;
    }
    adst[it * 256 + t] = o;
  }
}

// ---------------------------------------------------------------------------
// kpv: PURE GEMM out0 = att @ h.
// r13 diagnosis: B-tile re-reads (4 waves/block x 2048 blocks x 128 KB =
// 1.07 GB) were falling to L3 (~7 TB/s) because the 268 MB att f32 stream
// evicted the 2 MB ht from each XCD's 4 MB L2. Fix: NT loads for att (no
// reuse anyway -> don't allocate in L1/L2), keeping ht L2-resident so B
// reads hit L2 (34.5 TB/s).
// grid: (NROW/64)*KSPLIT blocks, 256 threads
// ---------------------------------------------------------------------------
__global__ __launch_bounds__(256, 8) void kpv(const __bf16* __restrict__ ht,
                                              const float* __restrict__ att,
                                              float* __restrict__ out0) {
  const int mb = blockIdx.x / KSPLIT;
  const int ks = blockIdx.x % KSPLIT;
  const int t    = threadIdx.x;
  const int w    = t >> 6;
  const int lane = t & 63;
  const int lr = lane & 15;
  const int lc = lane >> 4;
  const int row0 = mb * 64 + w * 16;
  const int arow = row0 + lr;
  const int j0 = ks * KCHUNK;

  const f32x4* abase = reinterpret_cast<const f32x4*>(
      att + (size_t)arow * NROW + j0 + lc * 8);
  const __bf16* hbase = ht + (size_t)lr * NROW + j0 + lc * 8;

  f32x4 acc[8];
  #pragma unroll
  for (int n = 0; n < 8; ++n) acc[n] = (f32x4){0.f, 0.f, 0.f, 0.f};

  // prefetch A for kk=0 (NT: bypass L1/L2 allocation, att has no reuse)
  f32x4 pa0 = __builtin_nontemporal_load(abase);
  f32x4 pa1 = __builtin_nontemporal_load(abase + 1);
  f32x4 pa2 = __builtin_nontemporal_load(abase + 8);
  f32x4 pa3 = __builtin_nontemporal_load(abase + 9);

  for (int kk = 0; kk < KCHUNK; kk += 64) {
    const f32x4 ca0 = pa0, ca1 = pa1, ca2 = pa2, ca3 = pa3;
    if (kk + 64 < KCHUNK) {
      const f32x4* ab = abase + ((kk + 64) >> 2);
      pa0 = __builtin_nontemporal_load(ab);
      pa1 = __builtin_nontemporal_load(ab + 1);
      pa2 = __builtin_nontemporal_load(ab + 8);
      pa3 = __builtin_nontemporal_load(ab + 9);
    }

    bf16x8 afrag[2];
    #pragma unroll
    for (int i2 = 0; i2 < 4; ++i2) {
      afrag[0][i2]     = (__bf16)ca0[i2];
      afrag[0][i2 + 4] = (__bf16)ca1[i2];
      afrag[1][i2]     = (__bf16)ca2[i2];
      afrag[1][i2 + 4] = (__bf16)ca3[i2];
    }

    #pragma unroll
    for (int n = 0; n < 8; ++n) {
      const __bf16* hb = hbase + (size_t)(n * 16) * NROW + kk;
      bf16x8 b0 = *reinterpret_cast<const bf16x8*>(hb);
      bf16x8 b1 = *reinterpret_cast<const bf16x8*>(hb + 32);
      acc[n] = __builtin_amdgcn_mfma_f32_16x16x32_bf16(afrag[0], b0, acc[n], 0, 0, 0);
      acc[n] = __builtin_amdgcn_mfma_f32_16x16x32_bf16(afrag[1], b1, acc[n], 0, 0, 0);
    }
  }

  #pragma unroll
  for (int n = 0; n < 8; ++n) {
    #pragma unroll
    for (int i2 = 0; i2 < 4; ++i2) {
      atomicAdd(&out0[(size_t)(row0 + lc * 4 + i2) * OUTF + n * 16 + lr],
                acc[n][i2]);
    }
  }
}

// ---------------------------------------------------------------------------
extern "C" void kernel_launch(void* const* d_in, const int* in_sizes, int n_in,
                              void* d_out, int out_size, void* d_ws, size_t ws_size,
                              hipStream_t stream) {
  const float* x   = (const float*)d_in[0];
  const int*   adj = (const int*)d_in[1];
  const float* W   = (const float*)d_in[2];
  const float* a   = (const float*)d_in[3];

  float* out0 = (float*)d_out;                       // 8192 x 128
  float* att  = (float*)d_out + (size_t)NROW * OUTF; // 8192 x 8192

  char* ws = (char*)d_ws;
  __bf16* ht = (__bf16*)ws;                               // 2 MB
  float* f1 = (float*)(ws + (2 << 20));
  float* f2 = (float*)(ws + (2 << 20) + 32 * 1024);

  hipMemsetAsync(out0, 0, (size_t)NROW * OUTF * sizeof(float), stream);
  k1<<<NROW / 32, 256, 0, stream>>>(x, W, a, ht, f1, f2);
  katt2<<<NROW, 256, 0, stream>>>(adj, f1, f2, att);
  kpv<<<(NROW / 64) * KSPLIT, 256, 0, stream>>>(ht, att, out0);
}

// Round 15
// 210.066 us; speedup vs baseline: 1.5058x; 1.4629x over previous
//
#include <hip/hip_runtime.h>
#include <hip/hip_bf16.h>

constexpr int NROW = 8192;
constexpr int INF  = 256;
constexpr int OUTF = 128;
constexpr int KSPLIT = 8;
constexpr int KCHUNK = NROW / KSPLIT; // 1024
constexpr int NIT    = KCHUNK / 64;   // 16 k-iterations per block
#define LOG2E 1.4426950408889634f

typedef __bf16 bf16x8 __attribute__((ext_vector_type(8)));
typedef float  f32x4  __attribute__((ext_vector_type(4)));
typedef int    i32x4  __attribute__((ext_vector_type(4)));

// ---------------------------------------------------------------------------
// k1: h = x@W (f32 accum); f1 = (h@a1)*log2e, f2 = (h@a2)*log2e; ht = h^T bf16
// grid: NROW/32 blocks, 256 threads
// ---------------------------------------------------------------------------
__global__ __launch_bounds__(256) void k1(const float* __restrict__ x,
                                          const float* __restrict__ W,
                                          const float* __restrict__ a,
                                          __bf16* __restrict__ ht,
                                          float* __restrict__ f1,
                                          float* __restrict__ f2) {
  __shared__ float xs[32][INF];   // 32 KB
  __shared__ float hs[32][OUTF];  // 16 KB
  const int t  = threadIdx.x;
  const int i0 = blockIdx.x * 32;

  const f32x4* xsrc = reinterpret_cast<const f32x4*>(x + (size_t)i0 * INF);
  f32x4* xdst = reinterpret_cast<f32x4*>(&xs[0][0]);
  #pragma unroll
  for (int u = 0; u < (32 * INF / 4) / 256; ++u)
    xdst[u * 256 + t] = xsrc[u * 256 + t];
  __syncthreads();

  const int c  = t & 127;
  const int rg = t >> 7;  // 0/1 -> rows rg*16 .. rg*16+15
  float acc[16];
  #pragma unroll
  for (int r = 0; r < 16; ++r) acc[r] = 0.f;
  for (int k = 0; k < INF; ++k) {
    float wv = W[k * OUTF + c];
    #pragma unroll
    for (int r = 0; r < 16; ++r) acc[r] += xs[rg * 16 + r][k] * wv;
  }
  #pragma unroll
  for (int r = 0; r < 16; ++r) hs[rg * 16 + r][c] = acc[r];
  __syncthreads();

  const int wv = t >> 6, lane = t & 63;
  for (int r = wv; r < 32; r += 4) {
    float h0 = hs[r][lane * 2], h1 = hs[r][lane * 2 + 1];
    float s1 = h0 * a[lane * 2] + h1 * a[lane * 2 + 1];
    float s2 = h0 * a[OUTF + lane * 2] + h1 * a[OUTF + lane * 2 + 1];
    #pragma unroll
    for (int off = 32; off; off >>= 1) {
      s1 += __shfl_down(s1, off);
      s2 += __shfl_down(s2, off);
    }
    if (lane == 0) { f1[i0 + r] = s1 * LOG2E; f2[i0 + r] = s2 * LOG2E; }
  }

  const int col = t >> 1, seg = t & 1;
  bf16x8 v0, v1;
  #pragma unroll
  for (int r = 0; r < 8; ++r) v0[r] = (__bf16)hs[seg * 16 + r][col];
  #pragma unroll
  for (int r = 0; r < 8; ++r) v1[r] = (__bf16)hs[seg * 16 + 8 + r][col];
  __bf16* hdst = ht + (size_t)col * NROW + i0 + seg * 16;
  *reinterpret_cast<bf16x8*>(hdst)     = v0;
  *reinterpret_cast<bf16x8*>(hdst + 8) = v1;
}

// ---------------------------------------------------------------------------
// katt2: one row per block, 8192 blocks. Phase 1 pure read; phase 2 pure
// write from registers (no loads between stores -> no vmcnt store drain).
// grid: NROW blocks, 256 threads
// ---------------------------------------------------------------------------
__global__ __launch_bounds__(256) void katt2(const int* __restrict__ adj,
                                             const float* __restrict__ f1,
                                             const float* __restrict__ f2,
                                             float* __restrict__ att) {
  const int i = blockIdx.x;
  const int t = threadIdx.x;
  const int lane = t & 63, wv = t >> 6;
  const float f1i = f1[i];
  const i32x4* arow = reinterpret_cast<const i32x4*>(adj + (size_t)i * NROW);
  const f32x4* f2v  = reinterpret_cast<const f32x4*>(f2);

  unsigned mynibs = 0;
  float acc = 0.f;
  f32x4 fv[8];
  #pragma unroll
  for (int it = 0; it < 8; ++it) {
    i32x4 av = __builtin_nontemporal_load(arow + it * 256 + t);
    fv[it] = f2v[it * 256 + t];
    unsigned nib = (av[0] > 0) | ((av[1] > 0) << 1) | ((av[2] > 0) << 2) |
                   ((av[3] > 0) << 3);
    mynibs |= nib << (it * 4);
    #pragma unroll
    for (int b = 0; b < 4; ++b) {
      float e = f1i + fv[it][b];
      e = e > 0.f ? e : 0.01f * e;
      acc += ((nib >> b) & 1u) ? __builtin_exp2f(e) : 0.f;
    }
  }

  #pragma unroll
  for (int off = 32; off; off >>= 1) acc += __shfl_down(acc, off);
  __shared__ float red[4];
  if (lane == 0) red[wv] = acc;
  __syncthreads();
  const float inv_s = 1.0f / (red[0] + red[1] + red[2] + red[3]);

  f32x4* adst = reinterpret_cast<f32x4*>(att + (size_t)i * NROW);
  #pragma unroll
  for (int it = 0; it < 8; ++it) {
    const unsigned nib = (mynibs >> (it * 4)) & 0xFu;
    f32x4 o;
    #pragma unroll
    for (int b = 0; b < 4; ++b) {
      float e = f1i + fv[it][b];
      e = e > 0.f ? e : 0.01f * e;
      o[b] = ((nib >> b) & 1u) ? __builtin_exp2f(e) * inv_s : 0.f;
    }
    adst[it * 256 + t] = o;
  }
}

// ---------------------------------------------------------------------------
// kpv: GEMM out0 = att @ h with LDS-staged, double-buffered B.
// r14 diagnosis: 20 VMEM insts/wave-iter with each MFMA waiting a fresh L2
// round trip; B loaded 4x redundantly per block (1.07 GB). Fix: B tile
// (128x64 bf16 = 16 KB) staged to LDS once per block (traffic /4), read as
// ds_read_b128 (lgkmcnt path, off the vmcnt queue). Rows padded to 72 bf16
// (144 B, 16B-aligned) -> ~2-way bank aliasing (free, m136). A stays NT-
// streamed 1-deep. Staging loads for t+1 issue before compute of t (T14),
// single barrier per iter. KSPLIT=8: atomics 32 MB. LDS 36 KB -> 4 blk/CU.
// grid: (NROW/64)*KSPLIT = 1024 blocks, 256 threads
// ---------------------------------------------------------------------------
__global__ __launch_bounds__(256, 4) void kpv(const __bf16* __restrict__ ht,
                                              const float* __restrict__ att,
                                              float* __restrict__ out0) {
  __shared__ __bf16 bs[2][128][72];  // 36 KB, double-buffered B tile
  const int mb = blockIdx.x / KSPLIT;
  const int ks = blockIdx.x % KSPLIT;
  const int t    = threadIdx.x;
  const int w    = t >> 6;
  const int lane = t & 63;
  const int lr = lane & 15;
  const int lc = lane >> 4;
  const int row0 = mb * 64 + w * 16;
  const int arow = row0 + lr;
  const int j0 = ks * KCHUNK;

  // staging map: thread t -> B row sr (0..127), cols sc..sc+31 (64 B)
  const int sr = t >> 1, sc = (t & 1) * 32;
  const __bf16* sgsrc = ht + (size_t)sr * NROW + j0 + sc;

  const f32x4* abase = reinterpret_cast<const f32x4*>(
      att + (size_t)arow * NROW + j0 + lc * 8);

  f32x4 acc[8];
  #pragma unroll
  for (int n = 0; n < 8; ++n) acc[n] = (f32x4){0.f, 0.f, 0.f, 0.f};

  // ---- prologue: stage tile 0, prefetch A(0) ----
  {
    bf16x8 st0, st1, st2, st3;
    st0 = *reinterpret_cast<const bf16x8*>(sgsrc);
    st1 = *reinterpret_cast<const bf16x8*>(sgsrc + 8);
    st2 = *reinterpret_cast<const bf16x8*>(sgsrc + 16);
    st3 = *reinterpret_cast<const bf16x8*>(sgsrc + 24);
    *reinterpret_cast<bf16x8*>(&bs[0][sr][sc])      = st0;
    *reinterpret_cast<bf16x8*>(&bs[0][sr][sc + 8])  = st1;
    *reinterpret_cast<bf16x8*>(&bs[0][sr][sc + 16]) = st2;
    *reinterpret_cast<bf16x8*>(&bs[0][sr][sc + 24]) = st3;
  }
  f32x4 pa0 = __builtin_nontemporal_load(abase);
  f32x4 pa1 = __builtin_nontemporal_load(abase + 1);
  f32x4 pa2 = __builtin_nontemporal_load(abase + 8);
  f32x4 pa3 = __builtin_nontemporal_load(abase + 9);
  __syncthreads();

  for (int it = 0; it < NIT; ++it) {
    const int cur = it & 1;
    const bool more = (it + 1) < NIT;

    // ---- issue staging loads for tile t+1 (vmcnt queue, drains late) ----
    bf16x8 st0, st1, st2, st3;
    if (more) {
      const __bf16* sg = sgsrc + (it + 1) * 64;
      st0 = *reinterpret_cast<const bf16x8*>(sg);
      st1 = *reinterpret_cast<const bf16x8*>(sg + 8);
      st2 = *reinterpret_cast<const bf16x8*>(sg + 16);
      st3 = *reinterpret_cast<const bf16x8*>(sg + 24);
    }

    // ---- A: consume prefetched, issue next ----
    const f32x4 ca0 = pa0, ca1 = pa1, ca2 = pa2, ca3 = pa3;
    if (more) {
      const f32x4* ab = abase + (it + 1) * 16;
      pa0 = __builtin_nontemporal_load(ab);
      pa1 = __builtin_nontemporal_load(ab + 1);
      pa2 = __builtin_nontemporal_load(ab + 8);
      pa3 = __builtin_nontemporal_load(ab + 9);
    }
    bf16x8 afrag[2];
    #pragma unroll
    for (int i2 = 0; i2 < 4; ++i2) {
      afrag[0][i2]     = (__bf16)ca0[i2];
      afrag[0][i2 + 4] = (__bf16)ca1[i2];
      afrag[1][i2]     = (__bf16)ca2[i2];
      afrag[1][i2 + 4] = (__bf16)ca3[i2];
    }

    // ---- B from LDS + MFMA ----
    #pragma unroll
    for (int n = 0; n < 8; ++n) {
      bf16x8 b0 = *reinterpret_cast<const bf16x8*>(&bs[cur][n * 16 + lr][lc * 8]);
      bf16x8 b1 = *reinterpret_cast<const bf16x8*>(&bs[cur][n * 16 + lr][lc * 8 + 32]);
      acc[n] = __builtin_amdgcn_mfma_f32_16x16x32_bf16(afrag[0], b0, acc[n], 0, 0, 0);
      acc[n] = __builtin_amdgcn_mfma_f32_16x16x32_bf16(afrag[1], b1, acc[n], 0, 0, 0);
    }

    // ---- write staged tile, one barrier per iter ----
    if (more) {
      *reinterpret_cast<bf16x8*>(&bs[cur ^ 1][sr][sc])      = st0;
      *reinterpret_cast<bf16x8*>(&bs[cur ^ 1][sr][sc + 8])  = st1;
      *reinterpret_cast<bf16x8*>(&bs[cur ^ 1][sr][sc + 16]) = st2;
      *reinterpret_cast<bf16x8*>(&bs[cur ^ 1][sr][sc + 24]) = st3;
      __syncthreads();
    }
  }

  #pragma unroll
  for (int n = 0; n < 8; ++n) {
    #pragma unroll
    for (int i2 = 0; i2 < 4; ++i2) {
      atomicAdd(&out0[(size_t)(row0 + lc * 4 + i2) * OUTF + n * 16 + lr],
                acc[n][i2]);
    }
  }
}

// ---------------------------------------------------------------------------
extern "C" void kernel_launch(void* const* d_in, const int* in_sizes, int n_in,
                              void* d_out, int out_size, void* d_ws, size_t ws_size,
                              hipStream_t stream) {
  const float* x   = (const float*)d_in[0];
  const int*   adj = (const int*)d_in[1];
  const float* W   = (const float*)d_in[2];
  const float* a   = (const float*)d_in[3];

  float* out0 = (float*)d_out;                       // 8192 x 128
  float* att  = (float*)d_out + (size_t)NROW * OUTF; // 8192 x 8192

  char* ws = (char*)d_ws;
  __bf16* ht = (__bf16*)ws;                               // 2 MB
  float* f1 = (float*)(ws + (2 << 20));
  float* f2 = (float*)(ws + (2 << 20) + 32 * 1024);

  hipMemsetAsync(out0, 0, (size_t)NROW * OUTF * sizeof(float), stream);
  k1<<<NROW / 32, 256, 0, stream>>>(x, W, a, ht, f1, f2);
  katt2<<<NROW, 256, 0, stream>>>(adj, f1, f2, att);
  kpv<<<(NROW / 64) * KSPLIT, 256, 0, stream>>>(ht, att, out0);
}

// Round 16
// 185.197 us; speedup vs baseline: 1.7080x; 1.1343x over previous
//
#include <hip/hip_runtime.h>
#include <hip/hip_bf16.h>

constexpr int NROW = 8192;
constexpr int INF  = 256;
constexpr int OUTF = 128;
constexpr int KSPLIT = 8;
constexpr int KCHUNK = NROW / KSPLIT; // 1024
constexpr int NIT    = KCHUNK / 64;   // 16 k-iterations per block
#define LOG2E 1.4426950408889634f

typedef __bf16 bf16x8 __attribute__((ext_vector_type(8)));
typedef float  f32x4  __attribute__((ext_vector_type(4)));
typedef int    i32x4  __attribute__((ext_vector_type(4)));
typedef unsigned long long u64;

// ---------------------------------------------------------------------------
// k1: h = x@W (f32 accum); f1 = (h@a1)*log2e, f2 = (h@a2)*log2e; ht = h^T bf16
// grid: NROW/32 blocks, 256 threads
// ---------------------------------------------------------------------------
__global__ __launch_bounds__(256) void k1(const float* __restrict__ x,
                                          const float* __restrict__ W,
                                          const float* __restrict__ a,
                                          __bf16* __restrict__ ht,
                                          float* __restrict__ f1,
                                          float* __restrict__ f2) {
  __shared__ float xs[32][INF];   // 32 KB
  __shared__ float hs[32][OUTF];  // 16 KB
  const int t  = threadIdx.x;
  const int i0 = blockIdx.x * 32;

  const f32x4* xsrc = reinterpret_cast<const f32x4*>(x + (size_t)i0 * INF);
  f32x4* xdst = reinterpret_cast<f32x4*>(&xs[0][0]);
  #pragma unroll
  for (int u = 0; u < (32 * INF / 4) / 256; ++u)
    xdst[u * 256 + t] = xsrc[u * 256 + t];
  __syncthreads();

  const int c  = t & 127;
  const int rg = t >> 7;  // 0/1 -> rows rg*16 .. rg*16+15
  float acc[16];
  #pragma unroll
  for (int r = 0; r < 16; ++r) acc[r] = 0.f;
  for (int k = 0; k < INF; ++k) {
    float wv = W[k * OUTF + c];
    #pragma unroll
    for (int r = 0; r < 16; ++r) acc[r] += xs[rg * 16 + r][k] * wv;
  }
  #pragma unroll
  for (int r = 0; r < 16; ++r) hs[rg * 16 + r][c] = acc[r];
  __syncthreads();

  const int wv = t >> 6, lane = t & 63;
  for (int r = wv; r < 32; r += 4) {
    float h0 = hs[r][lane * 2], h1 = hs[r][lane * 2 + 1];
    float s1 = h0 * a[lane * 2] + h1 * a[lane * 2 + 1];
    float s2 = h0 * a[OUTF + lane * 2] + h1 * a[OUTF + lane * 2 + 1];
    #pragma unroll
    for (int off = 32; off; off >>= 1) {
      s1 += __shfl_down(s1, off);
      s2 += __shfl_down(s2, off);
    }
    if (lane == 0) { f1[i0 + r] = s1 * LOG2E; f2[i0 + r] = s2 * LOG2E; }
  }

  const int col = t >> 1, seg = t & 1;
  bf16x8 v0, v1;
  #pragma unroll
  for (int r = 0; r < 8; ++r) v0[r] = (__bf16)hs[seg * 16 + r][col];
  #pragma unroll
  for (int r = 0; r < 8; ++r) v1[r] = (__bf16)hs[seg * 16 + 8 + r][col];
  __bf16* hdst = ht + (size_t)col * NROW + i0 + seg * 16;
  *reinterpret_cast<bf16x8*>(hdst)     = v0;
  *reinterpret_cast<bf16x8*>(hdst + 8) = v1;
}

// ---------------------------------------------------------------------------
// katt2: one row per block, 8192 blocks. Phase 1 pure read (f2 kept in
// registers); phase 1.5 emits the packed adjacency bitmask (8 MB ws) + row
// sum s; phase 2 pure register-fed write stream (no loads between stores ->
// no vmcnt store drain). 524 MB @ ~5.7 TB/s measured (r15) ~= copy ceiling.
// grid: NROW blocks, 256 threads
// ---------------------------------------------------------------------------
__global__ __launch_bounds__(256) void katt2(const int* __restrict__ adj,
                                             const float* __restrict__ f1,
                                             const float* __restrict__ f2,
                                             u64* __restrict__ mask,
                                             float* __restrict__ s,
                                             float* __restrict__ att) {
  const int i = blockIdx.x;
  const int t = threadIdx.x;
  const int lane = t & 63, wv = t >> 6;
  const float f1i = f1[i];
  const i32x4* arow = reinterpret_cast<const i32x4*>(adj + (size_t)i * NROW);
  const f32x4* f2v  = reinterpret_cast<const f32x4*>(f2);
  u64* mrow = mask + (size_t)i * 128;

  // ---- phase 1: pure read stream ----
  unsigned mynibs = 0;
  float acc = 0.f;
  f32x4 fv[8];
  #pragma unroll
  for (int it = 0; it < 8; ++it) {
    i32x4 av = __builtin_nontemporal_load(arow + it * 256 + t);
    fv[it] = f2v[it * 256 + t];
    unsigned nib = (av[0] > 0) | ((av[1] > 0) << 1) | ((av[2] > 0) << 2) |
                   ((av[3] > 0) << 3);
    mynibs |= nib << (it * 4);
    #pragma unroll
    for (int b = 0; b < 4; ++b) {
      float e = f1i + fv[it][b];
      e = e > 0.f ? e : 0.01f * e;
      acc += ((nib >> b) & 1u) ? __builtin_exp2f(e) : 0.f;
    }
  }

  // ---- phase 1.5: mask emission + row-sum reduction ----
  #pragma unroll
  for (int it = 0; it < 8; ++it) {
    u64 m = (u64)((mynibs >> (it * 4)) & 0xFu) << (4 * (lane & 15));
    #pragma unroll
    for (int d = 1; d < 16; d <<= 1) m |= __shfl_xor(m, d);
    if ((lane & 15) == 0) mrow[it * 16 + (t >> 4)] = m;
  }
  #pragma unroll
  for (int off = 32; off; off >>= 1) acc += __shfl_down(acc, off);
  __shared__ float red[4];
  if (lane == 0) red[wv] = acc;
  __syncthreads();
  const float srow = red[0] + red[1] + red[2] + red[3];
  if (t == 0) s[i] = srow;
  const float inv_s = 1.0f / srow;

  // ---- phase 2: pure write stream (no loads; fv in registers) ----
  f32x4* adst = reinterpret_cast<f32x4*>(att + (size_t)i * NROW);
  #pragma unroll
  for (int it = 0; it < 8; ++it) {
    const unsigned nib = (mynibs >> (it * 4)) & 0xFu;
    f32x4 o;
    #pragma unroll
    for (int b = 0; b < 4; ++b) {
      float e = f1i + fv[it][b];
      e = e > 0.f ? e : 0.01f * e;
      o[b] = ((nib >> b) & 1u) ? __builtin_exp2f(e) * inv_s : 0.f;
    }
    adst[it * 256 + t] = o;
  }
}

// ---------------------------------------------------------------------------
// kpv: out0 = P @ h with BOTH prior fixes combined:
//  - A (P) recomputed in-register from the 8 MB bitmask + LDS f2s (r4-r10
//    idea): A global traffic 268 MB -> 8 MB, all off the vmcnt path.
//  - B staged in LDS double-buffered (r15 fix): B traffic once per block,
//    ds_read_b128 on the lgkm path.
// Loop's only global ops: B staging from the 2 MB ht — which is now truly
// L2-resident because the att A-stream no longer flows through L2 at all.
// LDS: 36 (B dbuf) + 8.5 (mask, [64][17] pad: unpadded would put all 16
// row-groups on one bank) + 4 (f2s) = 48.5 KB -> 3 blocks/CU (occupancy
// proved non-binding: r13 35->80% occ = 0 gain).
// grid: (NROW/64)*KSPLIT = 1024 blocks, 256 threads
// ---------------------------------------------------------------------------
__global__ __launch_bounds__(256, 3) void kpv(const __bf16* __restrict__ ht,
                                              const float* __restrict__ f1,
                                              const float* __restrict__ f2,
                                              const float* __restrict__ sum,
                                              const u64* __restrict__ mask,
                                              float* __restrict__ out0) {
  __shared__ __bf16 bs[2][128][72];  // 36 KB, double-buffered B tile
  __shared__ float f2s[KCHUNK];      // 4 KB
  __shared__ u64 ms[64][17];         // 8.5 KB
  const int mb = blockIdx.x / KSPLIT;
  const int ks = blockIdx.x % KSPLIT;
  const int t    = threadIdx.x;
  const int w    = t >> 6;
  const int lane = t & 63;
  const int lr = lane & 15;
  const int lc = lane >> 4;
  const int row0 = mb * 64 + w * 16;
  const int arow = row0 + lr;
  const int j0 = ks * KCHUNK;

  // ---- prologue: stage f2 chunk, mask chunk, B tile 0 ----
  {
    reinterpret_cast<f32x4*>(f2s)[t] =
        reinterpret_cast<const f32x4*>(f2 + j0)[t];       // 4 KB
    const int r = t >> 2, q = (t & 3) * 4;                // mask: 32B/thread
    const u64* msrc = mask + (size_t)(mb * 64 + r) * 128 + (j0 >> 6) + q;
    ms[r][q]     = msrc[0];
    ms[r][q + 1] = msrc[1];
    ms[r][q + 2] = msrc[2];
    ms[r][q + 3] = msrc[3];
  }
  const int sr = t >> 1, sc = (t & 1) * 32;  // B staging map
  const __bf16* sgsrc = ht + (size_t)sr * NROW + j0 + sc;
  {
    bf16x8 st0 = *reinterpret_cast<const bf16x8*>(sgsrc);
    bf16x8 st1 = *reinterpret_cast<const bf16x8*>(sgsrc + 8);
    bf16x8 st2 = *reinterpret_cast<const bf16x8*>(sgsrc + 16);
    bf16x8 st3 = *reinterpret_cast<const bf16x8*>(sgsrc + 24);
    *reinterpret_cast<bf16x8*>(&bs[0][sr][sc])      = st0;
    *reinterpret_cast<bf16x8*>(&bs[0][sr][sc + 8])  = st1;
    *reinterpret_cast<bf16x8*>(&bs[0][sr][sc + 16]) = st2;
    *reinterpret_cast<bf16x8*>(&bs[0][sr][sc + 24]) = st3;
  }
  __syncthreads();

  const float f1r  = f1[arow];
  const int   rloc = w * 16 + lr;

  f32x4 acc[8];
  #pragma unroll
  for (int n = 0; n < 8; ++n) acc[n] = (f32x4){0.f, 0.f, 0.f, 0.f};

  for (int it = 0; it < NIT; ++it) {
    const int cur = it & 1;
    const bool more = (it + 1) < NIT;

    // ---- issue B staging loads for tile t+1 (only vmcnt ops in loop) ----
    bf16x8 st0, st1, st2, st3;
    if (more) {
      const __bf16* sg = sgsrc + (it + 1) * 64;
      st0 = *reinterpret_cast<const bf16x8*>(sg);
      st1 = *reinterpret_cast<const bf16x8*>(sg + 8);
      st2 = *reinterpret_cast<const bf16x8*>(sg + 16);
      st3 = *reinterpret_cast<const bf16x8*>(sg + 24);
    }

    // ---- A-fragments recomputed from mask + f2s (LDS + VALU only) ----
    const u64 mw = ms[rloc][it];
    const int kk = it * 64;
    bf16x8 afrag[2];
    #pragma unroll
    for (int h = 0; h < 2; ++h) {
      const unsigned bits = (unsigned)(mw >> (h * 32 + lc * 8)) & 0xFFu;
      const int base = kk + h * 32 + lc * 8;
      #pragma unroll
      for (int i2 = 0; i2 < 8; ++i2) {
        float e = f1r + f2s[base + i2];
        e = e > 0.f ? e : 0.01f * e;
        afrag[h][i2] = (__bf16)(((bits >> i2) & 1u) ? __builtin_exp2f(e) : 0.f);
      }
    }

    // ---- B from LDS + MFMA ----
    #pragma unroll
    for (int n = 0; n < 8; ++n) {
      bf16x8 b0 = *reinterpret_cast<const bf16x8*>(&bs[cur][n * 16 + lr][lc * 8]);
      bf16x8 b1 = *reinterpret_cast<const bf16x8*>(&bs[cur][n * 16 + lr][lc * 8 + 32]);
      acc[n] = __builtin_amdgcn_mfma_f32_16x16x32_bf16(afrag[0], b0, acc[n], 0, 0, 0);
      acc[n] = __builtin_amdgcn_mfma_f32_16x16x32_bf16(afrag[1], b1, acc[n], 0, 0, 0);
    }

    // ---- write staged tile, one barrier per iter ----
    if (more) {
      *reinterpret_cast<bf16x8*>(&bs[cur ^ 1][sr][sc])      = st0;
      *reinterpret_cast<bf16x8*>(&bs[cur ^ 1][sr][sc + 8])  = st1;
      *reinterpret_cast<bf16x8*>(&bs[cur ^ 1][sr][sc + 16]) = st2;
      *reinterpret_cast<bf16x8*>(&bs[cur ^ 1][sr][sc + 24]) = st3;
      __syncthreads();
    }
  }

  // ---- epilogue: scale by 1/s, atomic accumulate ----
  float inv_sD[4];
  #pragma unroll
  for (int i2 = 0; i2 < 4; ++i2) inv_sD[i2] = 1.0f / sum[row0 + lc * 4 + i2];
  #pragma unroll
  for (int n = 0; n < 8; ++n) {
    #pragma unroll
    for (int i2 = 0; i2 < 4; ++i2) {
      atomicAdd(&out0[(size_t)(row0 + lc * 4 + i2) * OUTF + n * 16 + lr],
                acc[n][i2] * inv_sD[i2]);
    }
  }
}

// ---------------------------------------------------------------------------
extern "C" void kernel_launch(void* const* d_in, const int* in_sizes, int n_in,
                              void* d_out, int out_size, void* d_ws, size_t ws_size,
                              hipStream_t stream) {
  const float* x   = (const float*)d_in[0];
  const int*   adj = (const int*)d_in[1];
  const float* W   = (const float*)d_in[2];
  const float* a   = (const float*)d_in[3];

  float* out0 = (float*)d_out;                       // 8192 x 128
  float* att  = (float*)d_out + (size_t)NROW * OUTF; // 8192 x 8192

  char* ws = (char*)d_ws;
  __bf16* ht = (__bf16*)ws;                                         // 2 MB
  u64* mask = (u64*)(ws + (2 << 20));                               // 8 MB
  float* f1 = (float*)(ws + (10 << 20));
  float* f2 = (float*)(ws + (10 << 20) + 32 * 1024);
  float* s  = (float*)(ws + (10 << 20) + 64 * 1024);

  hipMemsetAsync(out0, 0, (size_t)NROW * OUTF * sizeof(float), stream);
  k1<<<NROW / 32, 256, 0, stream>>>(x, W, a, ht, f1, f2);
  katt2<<<NROW, 256, 0, stream>>>(adj, f1, f2, mask, s, att);
  kpv<<<(NROW / 64) * KSPLIT, 256, 0, stream>>>(ht, f1, f2, s, mask, out0);
}